// Round 1
// baseline (261.909 us; speedup 1.0000x reference)
//
#include <hip/hip_runtime.h>
#include <cstddef>

#define HW   4096
#define CIN  256
#define NCAT 384   // 256 value + 64 off + 32 attn + 32 pad

// ---------------------------------------------------------------------------
// Prep: build transposed/concatenated weights in workspace.
// WcatT[c][n] (256 x 384), bcat[512], w_outT[c][o] (256 x 256)
// ---------------------------------------------------------------------------
__global__ __launch_bounds__(256)
void prep_kernel(const float* __restrict__ w_off, const float* __restrict__ b_off,
                 const float* __restrict__ w_attn, const float* __restrict__ b_attn,
                 const float* __restrict__ w_val, const float* __restrict__ b_val,
                 const float* __restrict__ w_out,
                 float* __restrict__ wcatT, float* __restrict__ bcat,
                 float* __restrict__ w_outT)
{
    int i = blockIdx.x * 256 + threadIdx.x;      // grid covers 256*384
    if (i < 256 * 384) {
        int c = i / 384, n = i % 384;
        float v;
        if (n < 256)      v = w_val[n * 256 + c];
        else if (n < 320) v = w_off[(n - 256) * 256 + c];
        else if (n < 352) v = w_attn[(n - 320) * 256 + c];
        else              v = 0.0f;
        wcatT[i] = v;
    }
    if (i < 256 * 256) {
        int c = i / 256, o = i % 256;
        w_outT[i] = w_out[o * 256 + c];
    }
    if (i < 512) {
        float v = 0.0f;
        if (i < 256)      v = b_val[i];
        else if (i < 320) v = b_off[i - 256];
        else if (i < 352) v = b_attn[i - 320];
        bcat[i] = v;
    }
}

// ---------------------------------------------------------------------------
// Shared GEMM core: 64(n) x 64(p) block tile, K=256 chunked by 64,
// 256 threads, 4x4 register tile per thread.
// inb: [256][4096] (channel-major input for one batch), wT: [256][NTOT]
// ---------------------------------------------------------------------------
template <int NTOT>
__device__ inline void gemm_core(const float* __restrict__ inb,
                                 const float* __restrict__ wT,
                                 float (*xs)[68], float (*wsb)[68],
                                 int p0, int nb, int tid, float acc[4][4])
{
    const int tn = tid & 15;          // n sub-tile
    const int tp = tid >> 4;          // p sub-tile
    const int lc = tid >> 4;          // load row
    const int lp = (tid & 15) << 2;   // load col (float4)
    const float* xbase = inb + p0 + lp;
    const float* wbase = wT + nb + lp;

    for (int kc = 0; kc < 256; kc += 64) {
        __syncthreads();
#pragma unroll
        for (int r = 0; r < 4; ++r) {
            int cc = lc + 16 * r;
            *(float4*)&xs[cc][lp]  = *(const float4*)&xbase[(kc + cc) * HW];
            *(float4*)&wsb[cc][lp] = *(const float4*)&wbase[(kc + cc) * NTOT];
        }
        __syncthreads();
#pragma unroll 16
        for (int cc = 0; cc < 64; ++cc) {
            float4 wv = *(const float4*)&wsb[cc][tn * 4];
            float4 xv = *(const float4*)&xs[cc][tp * 4];
            acc[0][0] += wv.x * xv.x; acc[0][1] += wv.x * xv.y; acc[0][2] += wv.x * xv.z; acc[0][3] += wv.x * xv.w;
            acc[1][0] += wv.y * xv.x; acc[1][1] += wv.y * xv.y; acc[1][2] += wv.y * xv.z; acc[1][3] += wv.y * xv.w;
            acc[2][0] += wv.z * xv.x; acc[2][1] += wv.z * xv.y; acc[2][2] += wv.z * xv.z; acc[2][3] += wv.z * xv.w;
            acc[3][0] += wv.w * xv.x; acc[3][1] += wv.w * xv.y; acc[3][2] += wv.w * xv.z; acc[3][3] += wv.w * xv.w;
        }
    }
}

// ---------------------------------------------------------------------------
// Kernel 1: fused value/offset/attn projections.
// grid = 8 (b) * 64 (ptile) * 6 (nblock) = 3072
// value -> value_t[(b*8+head)][p][c32]  (sample-friendly transposed layout)
// offsets -> off_ws[b][64][p], attn logits -> attn_ws[b][32][p]
// ---------------------------------------------------------------------------
__global__ __launch_bounds__(256, 4)
void qkv_kernel(const float* __restrict__ x, const float* __restrict__ wcatT,
                const float* __restrict__ bcat,
                float* __restrict__ value_t, float* __restrict__ off_ws,
                float* __restrict__ attn_ws)
{
    __shared__ float xs[64][68];
    __shared__ float wsb[64][68];
    const int bid   = blockIdx.x;
    const int nbi   = bid % 6;
    const int ptile = (bid / 6) & 63;
    const int b     = bid / (6 * 64);
    const int nb    = nbi * 64;
    const int p0    = ptile * 64;
    const int tid   = threadIdx.x;
    const int tn    = tid & 15;
    const int tp    = tid >> 4;

    float acc[4][4];
#pragma unroll
    for (int i = 0; i < 4; ++i) {
        float bv = bcat[nb + tn * 4 + i];
#pragma unroll
        for (int j = 0; j < 4; ++j) acc[i][j] = bv;
    }

    gemm_core<NCAT>(x + (size_t)b * CIN * HW, wcatT, xs, wsb, p0, nb, tid, acc);

    if (nbi < 4) {
        // value channels: n = nb + tn*4 + i; head = n/32, c32 = n%32
        const int n0   = nb + tn * 4;
        const int head = n0 >> 5;
        const int c32  = n0 & 31;
        float* vb = value_t + ((size_t)(b * 8 + head) * HW) * 32 + c32;
#pragma unroll
        for (int j = 0; j < 4; ++j) {
            int p = p0 + tp * 4 + j;
            float4 v = make_float4(acc[0][j], acc[1][j], acc[2][j], acc[3][j]);
            *(float4*)&vb[(size_t)p * 32] = v;
        }
    } else if (nbi == 4) {
#pragma unroll
        for (int i = 0; i < 4; ++i) {
            int och = tn * 4 + i;
            float4 v = make_float4(acc[i][0], acc[i][1], acc[i][2], acc[i][3]);
            *(float4*)&off_ws[(size_t)(b * 64 + och) * HW + p0 + tp * 4] = v;
        }
    } else {
        if (tn < 8) {
#pragma unroll
            for (int i = 0; i < 4; ++i) {
                int ach = tn * 4 + i;
                float4 v = make_float4(acc[i][0], acc[i][1], acc[i][2], acc[i][3]);
                *(float4*)&attn_ws[(size_t)(b * 32 + ach) * HW + p0 + tp * 4] = v;
            }
        }
    }
}

// ---------------------------------------------------------------------------
// Kernel 2: softmax over P=4 + bilinear sampling + weighted sum.
// One thread per (b, head, p). grid = 8*8*16 = 1024 blocks x 256.
// Writes weighted[b][head*32+c][p] (channel-major, coalesced over lanes).
// ---------------------------------------------------------------------------
__global__ __launch_bounds__(256)
void sample_kernel(const float* __restrict__ value_t, const float* __restrict__ off_ws,
                   const float* __restrict__ attn_ws, float* __restrict__ wgt)
{
    const int bid  = blockIdx.x;
    const int p    = (bid & 15) * 256 + threadIdx.x;
    const int head = (bid >> 4) & 7;
    const int b    = bid >> 7;
    const int h    = p >> 6;
    const int w    = p & 63;

    const float gx = w * (2.0f / 63.0f) - 1.0f;
    const float gy = h * (2.0f / 63.0f) - 1.0f;

    // softmax over the head's 4 points
    float l0 = attn_ws[(size_t)(b * 32 + head * 4 + 0) * HW + p];
    float l1 = attn_ws[(size_t)(b * 32 + head * 4 + 1) * HW + p];
    float l2 = attn_ws[(size_t)(b * 32 + head * 4 + 2) * HW + p];
    float l3 = attn_ws[(size_t)(b * 32 + head * 4 + 3) * HW + p];
    float m  = fmaxf(fmaxf(l0, l1), fmaxf(l2, l3));
    float e0 = __expf(l0 - m), e1 = __expf(l1 - m), e2 = __expf(l2 - m), e3 = __expf(l3 - m);
    float inv = 1.0f / (e0 + e1 + e2 + e3);
    float aw[4] = {e0 * inv, e1 * inv, e2 * inv, e3 * inv};

    float4 acc[8];
#pragma unroll
    for (int c = 0; c < 8; ++c) acc[c] = make_float4(0.f, 0.f, 0.f, 0.f);

    const float* vb = value_t + (size_t)(b * 8 + head) * HW * 32;

#pragma unroll
    for (int pt = 0; pt < 4; ++pt) {
        float ox = off_ws[(size_t)(b * 64 + (head * 4 + pt) * 2 + 0) * HW + p];
        float oy = off_ws[(size_t)(b * 64 + (head * 4 + pt) * 2 + 1) * HW + p];
        float ix = (gx + ox + 1.0f) * 31.5f;   // (g+1)*0.5*(W-1)
        float iy = (gy + oy + 1.0f) * 31.5f;
        float x0f = floorf(ix), y0f = floorf(iy);
        float wx1 = ix - x0f, wx0 = 1.0f - wx1;
        float wy1 = iy - y0f, wy0 = 1.0f - wy1;
        int x0 = (int)x0f, y0 = (int)y0f;
        int x1 = x0 + 1,   y1 = y0 + 1;
        float a = aw[pt];
        float vx0 = (x0 >= 0 && x0 <= 63) ? 1.f : 0.f;
        float vx1 = (x1 >= 0 && x1 <= 63) ? 1.f : 0.f;
        float vy0 = (y0 >= 0 && y0 <= 63) ? 1.f : 0.f;
        float vy1 = (y1 >= 0 && y1 <= 63) ? 1.f : 0.f;
        float w00 = a * wy0 * wx0 * vy0 * vx0;
        float w01 = a * wy0 * wx1 * vy0 * vx1;
        float w10 = a * wy1 * wx0 * vy1 * vx0;
        float w11 = a * wy1 * wx1 * vy1 * vx1;
        int cx0 = min(max(x0, 0), 63), cx1 = min(max(x1, 0), 63);
        int cy0 = min(max(y0, 0), 63), cy1 = min(max(y1, 0), 63);
        const float4* v00 = (const float4*)(vb + (size_t)(cy0 * 64 + cx0) * 32);
        const float4* v01 = (const float4*)(vb + (size_t)(cy0 * 64 + cx1) * 32);
        const float4* v10 = (const float4*)(vb + (size_t)(cy1 * 64 + cx0) * 32);
        const float4* v11 = (const float4*)(vb + (size_t)(cy1 * 64 + cx1) * 32);
#pragma unroll
        for (int c = 0; c < 8; ++c) {
            float4 s00 = v00[c], s01 = v01[c], s10 = v10[c], s11 = v11[c];
            acc[c].x += w00 * s00.x + w01 * s01.x + w10 * s10.x + w11 * s11.x;
            acc[c].y += w00 * s00.y + w01 * s01.y + w10 * s10.y + w11 * s11.y;
            acc[c].z += w00 * s00.z + w01 * s01.z + w10 * s10.z + w11 * s11.z;
            acc[c].w += w00 * s00.w + w01 * s01.w + w10 * s10.w + w11 * s11.w;
        }
    }

    float* wp = wgt + (size_t)(b * 256 + head * 32) * HW + p;
#pragma unroll
    for (int c = 0; c < 8; ++c) {
        wp[(size_t)(4 * c + 0) * HW] = acc[c].x;
        wp[(size_t)(4 * c + 1) * HW] = acc[c].y;
        wp[(size_t)(4 * c + 2) * HW] = acc[c].z;
        wp[(size_t)(4 * c + 3) * HW] = acc[c].w;
    }
}

// ---------------------------------------------------------------------------
// Kernel 3: output projection + bias + residual.
// grid = 8 (b) * 64 (ptile) * 4 (nblock) = 2048
// ---------------------------------------------------------------------------
__global__ __launch_bounds__(256, 4)
void outproj_kernel(const float* __restrict__ wgt, const float* __restrict__ w_outT,
                    const float* __restrict__ b_out, const float* __restrict__ x,
                    float* __restrict__ out)
{
    __shared__ float xs[64][68];
    __shared__ float wsb[64][68];
    const int bid   = blockIdx.x;
    const int nbi   = bid & 3;
    const int ptile = (bid >> 2) & 63;
    const int b     = bid >> 8;
    const int nb    = nbi * 64;
    const int p0    = ptile * 64;
    const int tid   = threadIdx.x;
    const int tn    = tid & 15;
    const int tp    = tid >> 4;

    float acc[4][4];
#pragma unroll
    for (int i = 0; i < 4; ++i)
#pragma unroll
        for (int j = 0; j < 4; ++j) acc[i][j] = 0.f;

    gemm_core<CIN>(wgt + (size_t)b * CIN * HW, w_outT, xs, wsb, p0, nb, tid, acc);

#pragma unroll
    for (int i = 0; i < 4; ++i) {
        int o = nb + tn * 4 + i;
        float bo = b_out[o];
        size_t base = (size_t)(b * 256 + o) * HW + p0 + tp * 4;
        float4 xv = *(const float4*)&x[base];
        float4 v = make_float4(acc[i][0] + bo + xv.x, acc[i][1] + bo + xv.y,
                               acc[i][2] + bo + xv.z, acc[i][3] + bo + xv.w);
        *(float4*)&out[base] = v;
    }
}

// ---------------------------------------------------------------------------
extern "C" void kernel_launch(void* const* d_in, const int* in_sizes, int n_in,
                              void* d_out, int out_size, void* d_ws, size_t ws_size,
                              hipStream_t stream)
{
    const float* x      = (const float*)d_in[0];
    const float* w_off  = (const float*)d_in[1];
    const float* b_off  = (const float*)d_in[2];
    const float* w_attn = (const float*)d_in[3];
    const float* b_attn = (const float*)d_in[4];
    const float* w_val  = (const float*)d_in[5];
    const float* b_val  = (const float*)d_in[6];
    const float* w_out  = (const float*)d_in[7];
    const float* b_out  = (const float*)d_in[8];
    float* out = (float*)d_out;

    float* ws      = (float*)d_ws;
    float* wcatT   = ws;                         // 256*384
    float* w_outT  = wcatT + 256 * 384;          // 256*256
    float* bcat    = w_outT + 256 * 256;         // 512
    float* value_t = bcat + 512;                 // 8*8*4096*32 = 8388608
    float* off_ws  = value_t + 8388608;          // 8*64*4096 = 2097152
    float* attn_ws = off_ws + 2097152;           // 8*32*4096 = 1048576
    float* wgt_ws  = attn_ws + 1048576;          // 8*256*4096 = 8388608

    prep_kernel<<<384, 256, 0, stream>>>(w_off, b_off, w_attn, b_attn,
                                         w_val, b_val, w_out, wcatT, bcat, w_outT);
    qkv_kernel<<<3072, 256, 0, stream>>>(x, wcatT, bcat, value_t, off_ws, attn_ws);
    sample_kernel<<<1024, 256, 0, stream>>>(value_t, off_ws, attn_ws, wgt_ws);
    outproj_kernel<<<2048, 256, 0, stream>>>(wgt_ws, w_outT, b_out, x, out);
}

// Round 2
// 188.692 us; speedup vs baseline: 1.3880x; 1.3880x over previous
//
#include <hip/hip_runtime.h>
#include <cstddef>

#define HW   4096
#define CIN  256
#define NCAT 384   // 256 value + 64 off + 32 attn + 32 pad

// ---------------------------------------------------------------------------
// Prep: build transposed/concatenated weights in workspace.
// WcatT[c][n] (256 x 384), bcat[512], w_outT[c][o] (256 x 256)
// ---------------------------------------------------------------------------
__global__ __launch_bounds__(256)
void prep_kernel(const float* __restrict__ w_off, const float* __restrict__ b_off,
                 const float* __restrict__ w_attn, const float* __restrict__ b_attn,
                 const float* __restrict__ w_val, const float* __restrict__ b_val,
                 const float* __restrict__ w_out,
                 float* __restrict__ wcatT, float* __restrict__ bcat,
                 float* __restrict__ w_outT)
{
    int i = blockIdx.x * 256 + threadIdx.x;      // grid covers 256*384
    if (i < 256 * 384) {
        int c = i / 384, n = i % 384;
        float v;
        if (n < 256)      v = w_val[n * 256 + c];
        else if (n < 320) v = w_off[(n - 256) * 256 + c];
        else if (n < 352) v = w_attn[(n - 320) * 256 + c];
        else              v = 0.0f;
        wcatT[i] = v;
    }
    if (i < 256 * 256) {
        int c = i / 256, o = i % 256;
        w_outT[i] = w_out[o * 256 + c];
    }
    if (i < 512) {
        float v = 0.0f;
        if (i < 256)      v = b_val[i];
        else if (i < 320) v = b_off[i - 256];
        else if (i < 352) v = b_attn[i - 320];
        bcat[i] = v;
    }
}

// ---------------------------------------------------------------------------
// Shared GEMM core: 64(n) x 64(p) block tile, K=256 chunked by 64,
// 256 threads, 4x4 register tile per thread.
// inb: [256][4096] (channel-major input for one batch), wT: [256][NTOT]
// ---------------------------------------------------------------------------
template <int NTOT>
__device__ inline void gemm_core(const float* __restrict__ inb,
                                 const float* __restrict__ wT,
                                 float (*xs)[68], float (*wsb)[68],
                                 int p0, int nb, int tid, float acc[4][4])
{
    const int tn = tid & 15;          // n sub-tile
    const int tp = tid >> 4;          // p sub-tile
    const int lc = tid >> 4;          // load row
    const int lp = (tid & 15) << 2;   // load col (float4)
    const float* xbase = inb + p0 + lp;
    const float* wbase = wT + nb + lp;

    for (int kc = 0; kc < 256; kc += 64) {
        __syncthreads();
#pragma unroll
        for (int r = 0; r < 4; ++r) {
            int cc = lc + 16 * r;
            *(float4*)&xs[cc][lp]  = *(const float4*)&xbase[(kc + cc) * HW];
            *(float4*)&wsb[cc][lp] = *(const float4*)&wbase[(kc + cc) * NTOT];
        }
        __syncthreads();
#pragma unroll 16
        for (int cc = 0; cc < 64; ++cc) {
            float4 wv = *(const float4*)&wsb[cc][tn * 4];
            float4 xv = *(const float4*)&xs[cc][tp * 4];
            acc[0][0] += wv.x * xv.x; acc[0][1] += wv.x * xv.y; acc[0][2] += wv.x * xv.z; acc[0][3] += wv.x * xv.w;
            acc[1][0] += wv.y * xv.x; acc[1][1] += wv.y * xv.y; acc[1][2] += wv.y * xv.z; acc[1][3] += wv.y * xv.w;
            acc[2][0] += wv.z * xv.x; acc[2][1] += wv.z * xv.y; acc[2][2] += wv.z * xv.z; acc[2][3] += wv.z * xv.w;
            acc[3][0] += wv.w * xv.x; acc[3][1] += wv.w * xv.y; acc[3][2] += wv.w * xv.z; acc[3][3] += wv.w * xv.w;
        }
    }
}

// ---------------------------------------------------------------------------
// Kernel 1: fused value/offset/attn projections.
// grid = 8 (b) * 64 (ptile) * 6 (nblock) = 3072
// value -> value_t[(b*8+head)][p][c32]  (sample-friendly transposed layout)
// offsets -> off_ws[b][64][p], attn logits -> attn_ws[b][32][p]
// ---------------------------------------------------------------------------
__global__ __launch_bounds__(256, 4)
void qkv_kernel(const float* __restrict__ x, const float* __restrict__ wcatT,
                const float* __restrict__ bcat,
                float* __restrict__ value_t, float* __restrict__ off_ws,
                float* __restrict__ attn_ws)
{
    __shared__ float xs[64][68];
    __shared__ float wsb[64][68];
    const int bid   = blockIdx.x;
    const int nbi   = bid % 6;
    const int ptile = (bid / 6) & 63;
    const int b     = bid / (6 * 64);
    const int nb    = nbi * 64;
    const int p0    = ptile * 64;
    const int tid   = threadIdx.x;
    const int tn    = tid & 15;
    const int tp    = tid >> 4;

    float acc[4][4];
#pragma unroll
    for (int i = 0; i < 4; ++i) {
        float bv = bcat[nb + tn * 4 + i];
#pragma unroll
        for (int j = 0; j < 4; ++j) acc[i][j] = bv;
    }

    gemm_core<NCAT>(x + (size_t)b * CIN * HW, wcatT, xs, wsb, p0, nb, tid, acc);

    if (nbi < 4) {
        // value channels: n = nb + tn*4 + i; head = n/32, c32 = n%32
        const int n0   = nb + tn * 4;
        const int head = n0 >> 5;
        const int c32  = n0 & 31;
        float* vb = value_t + ((size_t)(b * 8 + head) * HW) * 32 + c32;
#pragma unroll
        for (int j = 0; j < 4; ++j) {
            int p = p0 + tp * 4 + j;
            float4 v = make_float4(acc[0][j], acc[1][j], acc[2][j], acc[3][j]);
            *(float4*)&vb[(size_t)p * 32] = v;
        }
    } else if (nbi == 4) {
#pragma unroll
        for (int i = 0; i < 4; ++i) {
            int och = tn * 4 + i;
            float4 v = make_float4(acc[i][0], acc[i][1], acc[i][2], acc[i][3]);
            *(float4*)&off_ws[(size_t)(b * 64 + och) * HW + p0 + tp * 4] = v;
        }
    } else {
        if (tn < 8) {
#pragma unroll
            for (int i = 0; i < 4; ++i) {
                int ach = tn * 4 + i;
                float4 v = make_float4(acc[i][0], acc[i][1], acc[i][2], acc[i][3]);
                *(float4*)&attn_ws[(size_t)(b * 32 + ach) * HW + p0 + tp * 4] = v;
            }
        }
    }
}

// ---------------------------------------------------------------------------
// Kernel 2: softmax over P=4 + bilinear sampling + weighted sum.
// 8 lanes cooperate on one position (lane c4 = float4 channel slot), so each
// corner load is one contiguous 128B segment per 8-lane group.
// Block: 256 threads = 32 positions x 8 channel-slots of one (b, head).
// grid = 8 (b) * 8 (head) * 128 (ptile of 32) = 8192 blocks.
// Writes weighted[b][head*32+c][p] via a 32x32 LDS transpose tile.
// ---------------------------------------------------------------------------
__global__ __launch_bounds__(256)
void sample_kernel(const float* __restrict__ value_t, const float* __restrict__ off_ws,
                   const float* __restrict__ attn_ws, float* __restrict__ wgt)
{
    __shared__ float tile[32][33];

    const int bid    = blockIdx.x;
    const int ptile  = bid & 127;
    const int head   = (bid >> 7) & 7;
    const int b      = bid >> 10;
    const int tid    = threadIdx.x;
    const int c4     = tid & 7;        // which float4 of the 32 channels
    const int posIdx = tid >> 3;       // 0..31
    const int p      = ptile * 32 + posIdx;
    const int h      = p >> 6;
    const int w      = p & 63;

    const float gx = w * (2.0f / 63.0f) - 1.0f;
    const float gy = h * (2.0f / 63.0f) - 1.0f;

    // softmax over the head's 4 points (redundant across the 8 lanes; cheap)
    float l0 = attn_ws[(size_t)(b * 32 + head * 4 + 0) * HW + p];
    float l1 = attn_ws[(size_t)(b * 32 + head * 4 + 1) * HW + p];
    float l2 = attn_ws[(size_t)(b * 32 + head * 4 + 2) * HW + p];
    float l3 = attn_ws[(size_t)(b * 32 + head * 4 + 3) * HW + p];
    float m  = fmaxf(fmaxf(l0, l1), fmaxf(l2, l3));
    float e0 = __expf(l0 - m), e1 = __expf(l1 - m), e2 = __expf(l2 - m), e3 = __expf(l3 - m);
    float inv = 1.0f / (e0 + e1 + e2 + e3);
    float aw[4] = {e0 * inv, e1 * inv, e2 * inv, e3 * inv};

    float4 acc = make_float4(0.f, 0.f, 0.f, 0.f);
    const float* vb = value_t + (size_t)(b * 8 + head) * HW * 32 + c4 * 4;

#pragma unroll
    for (int pt = 0; pt < 4; ++pt) {
        float ox = off_ws[(size_t)(b * 64 + (head * 4 + pt) * 2 + 0) * HW + p];
        float oy = off_ws[(size_t)(b * 64 + (head * 4 + pt) * 2 + 1) * HW + p];
        float ix = (gx + ox + 1.0f) * 31.5f;   // (g+1)*0.5*(W-1)
        float iy = (gy + oy + 1.0f) * 31.5f;
        float x0f = floorf(ix), y0f = floorf(iy);
        float wx1 = ix - x0f, wx0 = 1.0f - wx1;
        float wy1 = iy - y0f, wy0 = 1.0f - wy1;
        int x0 = (int)x0f, y0 = (int)y0f;
        int x1 = x0 + 1,   y1 = y0 + 1;
        float a = aw[pt];
        float vx0 = (x0 >= 0 && x0 <= 63) ? 1.f : 0.f;
        float vx1 = (x1 >= 0 && x1 <= 63) ? 1.f : 0.f;
        float vy0 = (y0 >= 0 && y0 <= 63) ? 1.f : 0.f;
        float vy1 = (y1 >= 0 && y1 <= 63) ? 1.f : 0.f;
        float w00 = a * wy0 * wx0 * vy0 * vx0;
        float w01 = a * wy0 * wx1 * vy0 * vx1;
        float w10 = a * wy1 * wx0 * vy1 * vx0;
        float w11 = a * wy1 * wx1 * vy1 * vx1;
        int cx0 = min(max(x0, 0), 63), cx1 = min(max(x1, 0), 63);
        int cy0 = min(max(y0, 0), 63), cy1 = min(max(y1, 0), 63);
        float4 s00 = *(const float4*)&vb[(size_t)(cy0 * 64 + cx0) * 32];
        float4 s01 = *(const float4*)&vb[(size_t)(cy0 * 64 + cx1) * 32];
        float4 s10 = *(const float4*)&vb[(size_t)(cy1 * 64 + cx0) * 32];
        float4 s11 = *(const float4*)&vb[(size_t)(cy1 * 64 + cx1) * 32];
        acc.x += w00 * s00.x + w01 * s01.x + w10 * s10.x + w11 * s11.x;
        acc.y += w00 * s00.y + w01 * s01.y + w10 * s10.y + w11 * s11.y;
        acc.z += w00 * s00.z + w01 * s01.z + w10 * s10.z + w11 * s11.z;
        acc.w += w00 * s00.w + w01 * s01.w + w10 * s10.w + w11 * s11.w;
    }

    // transpose through LDS: tile[channel][position]
    tile[c4 * 4 + 0][posIdx] = acc.x;
    tile[c4 * 4 + 1][posIdx] = acc.y;
    tile[c4 * 4 + 2][posIdx] = acc.z;
    tile[c4 * 4 + 3][posIdx] = acc.w;
    __syncthreads();

    // coalesced write-out: thread (oc, sub) writes 4 consecutive positions
    const int oc  = tid >> 3;   // 0..31 channel
    const int sub = tid & 7;    // 0..7 -> positions sub*4..sub*4+3
    float4 v = make_float4(tile[oc][sub * 4 + 0], tile[oc][sub * 4 + 1],
                           tile[oc][sub * 4 + 2], tile[oc][sub * 4 + 3]);
    *(float4*)&wgt[(size_t)(b * 256 + head * 32 + oc) * HW + ptile * 32 + sub * 4] = v;
}

// ---------------------------------------------------------------------------
// Kernel 3: output projection + bias + residual.
// grid = 8 (b) * 64 (ptile) * 4 (nblock) = 2048
// ---------------------------------------------------------------------------
__global__ __launch_bounds__(256, 4)
void outproj_kernel(const float* __restrict__ wgt, const float* __restrict__ w_outT,
                    const float* __restrict__ b_out, const float* __restrict__ x,
                    float* __restrict__ out)
{
    __shared__ float xs[64][68];
    __shared__ float wsb[64][68];
    const int bid   = blockIdx.x;
    const int nbi   = bid & 3;
    const int ptile = (bid >> 2) & 63;
    const int b     = bid >> 8;
    const int nb    = nbi * 64;
    const int p0    = ptile * 64;
    const int tid   = threadIdx.x;
    const int tn    = tid & 15;
    const int tp    = tid >> 4;

    float acc[4][4];
#pragma unroll
    for (int i = 0; i < 4; ++i)
#pragma unroll
        for (int j = 0; j < 4; ++j) acc[i][j] = 0.f;

    gemm_core<CIN>(wgt + (size_t)b * CIN * HW, w_outT, xs, wsb, p0, nb, tid, acc);

#pragma unroll
    for (int i = 0; i < 4; ++i) {
        int o = nb + tn * 4 + i;
        float bo = b_out[o];
        size_t base = (size_t)(b * 256 + o) * HW + p0 + tp * 4;
        float4 xv = *(const float4*)&x[base];
        float4 v = make_float4(acc[i][0] + bo + xv.x, acc[i][1] + bo + xv.y,
                               acc[i][2] + bo + xv.z, acc[i][3] + bo + xv.w);
        *(float4*)&out[base] = v;
    }
}

// ---------------------------------------------------------------------------
extern "C" void kernel_launch(void* const* d_in, const int* in_sizes, int n_in,
                              void* d_out, int out_size, void* d_ws, size_t ws_size,
                              hipStream_t stream)
{
    const float* x      = (const float*)d_in[0];
    const float* w_off  = (const float*)d_in[1];
    const float* b_off  = (const float*)d_in[2];
    const float* w_attn = (const float*)d_in[3];
    const float* b_attn = (const float*)d_in[4];
    const float* w_val  = (const float*)d_in[5];
    const float* b_val  = (const float*)d_in[6];
    const float* w_out  = (const float*)d_in[7];
    const float* b_out  = (const float*)d_in[8];
    float* out = (float*)d_out;

    float* ws      = (float*)d_ws;
    float* wcatT   = ws;                         // 256*384
    float* w_outT  = wcatT + 256 * 384;          // 256*256
    float* bcat    = w_outT + 256 * 256;         // 512
    float* value_t = bcat + 512;                 // 8*8*4096*32 = 8388608
    float* off_ws  = value_t + 8388608;          // 8*64*4096 = 2097152
    float* attn_ws = off_ws + 2097152;           // 8*32*4096 = 1048576
    float* wgt_ws  = attn_ws + 1048576;          // 8*256*4096 = 8388608

    prep_kernel<<<384, 256, 0, stream>>>(w_off, b_off, w_attn, b_attn,
                                         w_val, b_val, w_out, wcatT, bcat, w_outT);
    qkv_kernel<<<3072, 256, 0, stream>>>(x, wcatT, bcat, value_t, off_ws, attn_ws);
    sample_kernel<<<8192, 256, 0, stream>>>(value_t, off_ws, attn_ws, wgt_ws);
    outproj_kernel<<<2048, 256, 0, stream>>>(wgt_ws, w_outT, b_out, x, out);
}

// Round 3
// 89.038 us; speedup vs baseline: 2.9416x; 2.1192x over previous
//
#include <hip/hip_runtime.h>
#include <cstddef>

#define HW 4096

typedef __attribute__((ext_vector_type(8))) short short8v;   // 8 bf16
typedef __attribute__((ext_vector_type(4))) float f32x4;     // 4 fp32

__device__ inline unsigned short f2bf(float f) {
    unsigned int u = __float_as_uint(f);
    u += 0x7FFFu + ((u >> 16) & 1u);
    return (unsigned short)(u >> 16);
}
__device__ inline float bf2f(unsigned short s) {
    return __uint_as_float(((unsigned int)s) << 16);
}

#define GLOAD_LDS16(gp, lp) __builtin_amdgcn_global_load_lds( \
    (const __attribute__((address_space(1))) unsigned int*)(gp), \
    (__attribute__((address_space(3))) unsigned int*)(lp), 16, 0, 0)

// ---------------------------------------------------------------------------
// Stage one 128x64 bf16 tile (rows of 64 bf16 = 128B) from row-major [*][256]
// global (row offset pre-applied) into LDS, with inverse-swizzled source so a
// swizzled ds_read_b128 (byte ^= (row&7)<<4) is bank-conflict-free.
// Per wave: 4 calls x 1024B (8 rows each). 256 threads = 4 waves cover 128 rows.
// ---------------------------------------------------------------------------
__device__ inline void stage_tile(const unsigned short* __restrict__ g,
                                  unsigned short* lds, int kc, int wid, int lane)
{
    const int r8   = lane >> 3;               // row within 8-row group
    const int slot = (lane & 7) ^ r8;         // inverse-swizzled 16B slot
    const unsigned short* src = g + (wid * 32 + r8) * 256 + kc + slot * 8;
#pragma unroll
    for (int i = 0; i < 4; ++i) {
        GLOAD_LDS16(src + i * 8 * 256, lds + (wid * 32 + i * 8) * 64);
    }
}

// read one MFMA A/B fragment (8 bf16) from a [128][64] bf16 LDS tile
__device__ inline short8v read_frag(const unsigned short* lds, int row, int kbyte, int lane)
{
    const char* p = (const char*)lds + row * 128 + (kbyte ^ ((lane & 7) * 16));
    return *(const short8v*)p;
}

// ---------------------------------------------------------------------------
// Prep: bf16 weights (row-major, no transpose), lo-plane for aux weights,
// padded fp32 bias vector.
// wcat_bf[384][256]: rows 0-255 w_val, 256-319 w_off, 320-351 w_attn, 352-383 zero
// ---------------------------------------------------------------------------
__global__ __launch_bounds__(256)
void prep_kernel(const float* __restrict__ w_off, const float* __restrict__ b_off,
                 const float* __restrict__ w_attn, const float* __restrict__ b_attn,
                 const float* __restrict__ w_val, const float* __restrict__ b_val,
                 const float* __restrict__ w_out,
                 unsigned short* __restrict__ wcat_bf, unsigned short* __restrict__ wauxlo,
                 unsigned short* __restrict__ wout_bf, float* __restrict__ bcat)
{
    int i = blockIdx.x * 256 + threadIdx.x;
    if (i < 384 * 256) {
        int n = i >> 8, k = i & 255;
        float v;
        if (n < 256)      v = w_val[n * 256 + k];
        else if (n < 320) v = w_off[(n - 256) * 256 + k];
        else if (n < 352) v = w_attn[(n - 320) * 256 + k];
        else              v = 0.0f;
        unsigned short hi = f2bf(v);
        wcat_bf[i] = hi;
        if (n >= 256) wauxlo[(n - 256) * 256 + k] = f2bf(v - bf2f(hi));
    }
    if (i < 256 * 256) wout_bf[i] = f2bf(w_out[i]);
    if (i < 512) {
        float v = 0.0f;
        if (i < 256)      v = b_val[i];
        else if (i < 320) v = b_off[i - 256];
        else if (i < 352) v = b_attn[i - 320];
        bcat[i] = v;
    }
}

// ---------------------------------------------------------------------------
// Transpose x: fp32 [b][c][4096] -> bf16 hi/lo [b][p][256]
// 64ch x 64pos tile per block; grid = 8 * 4 * 64 = 2048
// ---------------------------------------------------------------------------
__global__ __launch_bounds__(256)
void transpose_kernel(const float* __restrict__ x,
                      unsigned short* __restrict__ xhi, unsigned short* __restrict__ xlo)
{
    __shared__ float t[64][65];
    const int bid = blockIdx.x;
    const int pt = bid & 63, ct = (bid >> 6) & 3, b = bid >> 8;
    const int tid = threadIdx.x;
    const int rr = tid >> 4, c4 = (tid & 15) * 4;

    const float* src = x + ((size_t)(b * 256 + ct * 64)) * HW + pt * 64;
#pragma unroll
    for (int j = 0; j < 4; ++j) {
        float4 v = *(const float4*)&src[(size_t)(j * 16 + rr) * HW + c4];
        t[j * 16 + rr][c4 + 0] = v.x; t[j * 16 + rr][c4 + 1] = v.y;
        t[j * 16 + rr][c4 + 2] = v.z; t[j * 16 + rr][c4 + 3] = v.w;
    }
    __syncthreads();

    const size_t obase = ((size_t)b * HW + pt * 64) * 256 + ct * 64;
#pragma unroll
    for (int j = 0; j < 4; ++j) {
        int p = j * 16 + rr;
        float f0 = t[c4 + 0][p], f1 = t[c4 + 1][p], f2 = t[c4 + 2][p], f3 = t[c4 + 3][p];
        ushort4 hi = make_ushort4(f2bf(f0), f2bf(f1), f2bf(f2), f2bf(f3));
        ushort4 lo = make_ushort4(f2bf(f0 - bf2f(hi.x)), f2bf(f1 - bf2f(hi.y)),
                                  f2bf(f2 - bf2f(hi.z)), f2bf(f3 - bf2f(hi.w)));
        *(ushort4*)&xhi[obase + (size_t)p * 256 + c4] = hi;
        *(ushort4*)&xlo[obase + (size_t)p * 256 + c4] = lo;
    }
}

// ---------------------------------------------------------------------------
// MFMA mainloop: 128(M) x 128(N) tile, K=256 in 4 steps of 64.
// 4 waves (2x2), each 64x64 = 4x4 fragments of 16x16x32.
// ---------------------------------------------------------------------------
__device__ inline void mfma_loop2(const unsigned short* __restrict__ Ag,
                                  const unsigned short* __restrict__ Bg,
                                  unsigned short* Al, unsigned short* Bl,
                                  int wid, int lane, int wm, int wn, f32x4 acc[4][4])
{
    const int mloc = lane & 15, ksel = lane >> 4;
#pragma unroll
    for (int kc = 0; kc < 256; kc += 64) {
        if (kc) __syncthreads();
        stage_tile(Ag, Al, kc, wid, lane);
        stage_tile(Bg, Bl, kc, wid, lane);
        __syncthreads();
#pragma unroll
        for (int kk = 0; kk < 2; ++kk) {
            const int kb = kk * 64 + ksel * 16;
            short8v a[4], bb[4];
#pragma unroll
            for (int f = 0; f < 4; ++f) a[f]  = read_frag(Al, wm * 64 + f * 16 + mloc, kb, lane);
#pragma unroll
            for (int f = 0; f < 4; ++f) bb[f] = read_frag(Bl, wn * 64 + f * 16 + mloc, kb, lane);
#pragma unroll
            for (int fm = 0; fm < 4; ++fm)
#pragma unroll
                for (int fn = 0; fn < 4; ++fn)
                    acc[fm][fn] = __builtin_amdgcn_mfma_f32_16x16x32_bf16(a[fm], bb[fn], acc[fm][fn], 0, 0, 0);
        }
    }
}

// ---------------------------------------------------------------------------
// GEMM1a: value projection. M=256 (2 tiles), N=4096 per batch.
// grid = 8(b) * 2(mt) * 32(pt) = 512. Output bf16 value_bf[(b*8+head)][p][c32].
// ---------------------------------------------------------------------------
__global__ __launch_bounds__(256)
void value_gemm(const unsigned short* __restrict__ wcat_bf, const unsigned short* __restrict__ xhi,
                const float* __restrict__ bcat, unsigned short* __restrict__ value_bf)
{
    __shared__ unsigned short Al[128 * 64];
    __shared__ unsigned short Bl[128 * 64];
    const int bid = blockIdx.x;
    const int pt = bid & 31, mt = (bid >> 5) & 1, b = bid >> 6;
    const int tid = threadIdx.x, wid = tid >> 6, lane = tid & 63;
    const int wm = wid >> 1, wn = wid & 1;
    const int mloc = lane & 15, ksel = lane >> 4;

    const unsigned short* Ag = wcat_bf + mt * 128 * 256;
    const unsigned short* Bg = xhi + ((size_t)b * HW + pt * 128) * 256;

    f32x4 acc[4][4];
#pragma unroll
    for (int fm = 0; fm < 4; ++fm) {
        float4 bv = *(const float4*)&bcat[mt * 128 + wm * 64 + fm * 16 + ksel * 4];
#pragma unroll
        for (int fn = 0; fn < 4; ++fn) acc[fm][fn] = (f32x4){bv.x, bv.y, bv.z, bv.w};
    }

    mfma_loop2(Ag, Bg, Al, Bl, wid, lane, wm, wn, acc);

#pragma unroll
    for (int fm = 0; fm < 4; ++fm) {
        const int ch = mt * 128 + wm * 64 + fm * 16 + ksel * 4;
        const int head = ch >> 5, c32 = ch & 31;
#pragma unroll
        for (int fn = 0; fn < 4; ++fn) {
            const int p = pt * 128 + wn * 64 + fn * 16 + mloc;
            f32x4 v = acc[fm][fn];
            ushort4 st = make_ushort4(f2bf(v[0]), f2bf(v[1]), f2bf(v[2]), f2bf(v[3]));
            *(ushort4*)&value_bf[(((size_t)(b * 8 + head)) * HW + p) * 32 + c32] = st;
        }
    }
}

// ---------------------------------------------------------------------------
// GEMM1b: offsets+attn with split-bf16 (3-term) for near-fp32 precision.
// M=128 (64 off + 32 attn + 32 pad), grid = 8(b) * 32(pt) = 256.
// ---------------------------------------------------------------------------
__global__ __launch_bounds__(256)
void offattn_gemm(const unsigned short* __restrict__ wcat_bf, const unsigned short* __restrict__ wauxlo,
                  const unsigned short* __restrict__ xhi, const unsigned short* __restrict__ xlo,
                  const float* __restrict__ bcat,
                  float* __restrict__ off_ws, float* __restrict__ attn_ws)
{
    __shared__ unsigned short Ah[128 * 64];
    __shared__ unsigned short Alo[128 * 64];
    __shared__ unsigned short Bh[128 * 64];
    __shared__ unsigned short Blo[128 * 64];
    const int bid = blockIdx.x;
    const int pt = bid & 31, b = bid >> 5;
    const int tid = threadIdx.x, wid = tid >> 6, lane = tid & 63;
    const int wm = wid >> 1, wn = wid & 1;
    const int mloc = lane & 15, ksel = lane >> 4;

    const unsigned short* Ahg = wcat_bf + 256 * 256;          // aux rows 256..383
    const unsigned short* Alg = wauxlo;
    const unsigned short* Bhg = xhi + ((size_t)b * HW + pt * 128) * 256;
    const unsigned short* Blg = xlo + ((size_t)b * HW + pt * 128) * 256;

    f32x4 acc[4][4];
#pragma unroll
    for (int fm = 0; fm < 4; ++fm) {
        float4 bv = *(const float4*)&bcat[256 + wm * 64 + fm * 16 + ksel * 4];
#pragma unroll
        for (int fn = 0; fn < 4; ++fn) acc[fm][fn] = (f32x4){bv.x, bv.y, bv.z, bv.w};
    }

#pragma unroll
    for (int kc = 0; kc < 256; kc += 64) {
        if (kc) __syncthreads();
        stage_tile(Ahg, Ah, kc, wid, lane);
        stage_tile(Alg, Alo, kc, wid, lane);
        stage_tile(Bhg, Bh, kc, wid, lane);
        stage_tile(Blg, Blo, kc, wid, lane);
        __syncthreads();
#pragma unroll
        for (int kk = 0; kk < 2; ++kk) {
            const int kb = kk * 64 + ksel * 16;
            short8v ah[4], al[4], bh[4], bl[4];
#pragma unroll
            for (int f = 0; f < 4; ++f) {
                ah[f] = read_frag(Ah,  wm * 64 + f * 16 + mloc, kb, lane);
                al[f] = read_frag(Alo, wm * 64 + f * 16 + mloc, kb, lane);
                bh[f] = read_frag(Bh,  wn * 64 + f * 16 + mloc, kb, lane);
                bl[f] = read_frag(Blo, wn * 64 + f * 16 + mloc, kb, lane);
            }
#pragma unroll
            for (int fm = 0; fm < 4; ++fm)
#pragma unroll
                for (int fn = 0; fn < 4; ++fn) {
                    acc[fm][fn] = __builtin_amdgcn_mfma_f32_16x16x32_bf16(ah[fm], bh[fn], acc[fm][fn], 0, 0, 0);
                    acc[fm][fn] = __builtin_amdgcn_mfma_f32_16x16x32_bf16(ah[fm], bl[fn], acc[fm][fn], 0, 0, 0);
                    acc[fm][fn] = __builtin_amdgcn_mfma_f32_16x16x32_bf16(al[fm], bh[fn], acc[fm][fn], 0, 0, 0);
                }
        }
    }

#pragma unroll
    for (int fm = 0; fm < 4; ++fm) {
        const int chb = wm * 64 + fm * 16 + ksel * 4;
#pragma unroll
        for (int fn = 0; fn < 4; ++fn) {
            const int p = pt * 128 + wn * 64 + fn * 16 + mloc;
            f32x4 v = acc[fm][fn];
#pragma unroll
            for (int r = 0; r < 4; ++r) {
                int ch = chb + r;
                if (ch < 64)       off_ws[((size_t)(b * 64 + ch)) * HW + p] = v[r];
                else if (ch < 96)  attn_ws[((size_t)(b * 32 + (ch - 64))) * HW + p] = v[r];
            }
        }
    }
}

// ---------------------------------------------------------------------------
// Sampling: softmax(P=4) + bilinear gather + weighted sum.
// 8 lanes/position (c4 = float4-of-32ch slot). Writes bf16 wgt_t[b][p][256].
// grid = 8(b) * 8(head) * 128(ptile of 32) = 8192
// ---------------------------------------------------------------------------
__global__ __launch_bounds__(256)
void sample_kernel(const unsigned short* __restrict__ value_bf, const float* __restrict__ off_ws,
                   const float* __restrict__ attn_ws, unsigned short* __restrict__ wgt_t)
{
    const int bid    = blockIdx.x;
    const int ptile  = bid & 127;
    const int head   = (bid >> 7) & 7;
    const int b      = bid >> 10;
    const int tid    = threadIdx.x;
    const int c4     = tid & 7;
    const int posIdx = tid >> 3;
    const int p      = ptile * 32 + posIdx;
    const int h      = p >> 6;
    const int w      = p & 63;

    const float gx = w * (2.0f / 63.0f) - 1.0f;
    const float gy = h * (2.0f / 63.0f) - 1.0f;

    float l0 = attn_ws[(size_t)(b * 32 + head * 4 + 0) * HW + p];
    float l1 = attn_ws[(size_t)(b * 32 + head * 4 + 1) * HW + p];
    float l2 = attn_ws[(size_t)(b * 32 + head * 4 + 2) * HW + p];
    float l3 = attn_ws[(size_t)(b * 32 + head * 4 + 3) * HW + p];
    float m  = fmaxf(fmaxf(l0, l1), fmaxf(l2, l3));
    float e0 = __expf(l0 - m), e1 = __expf(l1 - m), e2 = __expf(l2 - m), e3 = __expf(l3 - m);
    float inv = 1.0f / (e0 + e1 + e2 + e3);
    float aw[4] = {e0 * inv, e1 * inv, e2 * inv, e3 * inv};

    float4 acc = make_float4(0.f, 0.f, 0.f, 0.f);
    const unsigned short* vb = value_bf + (size_t)(b * 8 + head) * HW * 32 + c4 * 4;

#pragma unroll
    for (int pt = 0; pt < 4; ++pt) {
        float ox = off_ws[(size_t)(b * 64 + (head * 4 + pt) * 2 + 0) * HW + p];
        float oy = off_ws[(size_t)(b * 64 + (head * 4 + pt) * 2 + 1) * HW + p];
        float ix = (gx + ox + 1.0f) * 31.5f;
        float iy = (gy + oy + 1.0f) * 31.5f;
        float x0f = floorf(ix), y0f = floorf(iy);
        float wx1 = ix - x0f, wx0 = 1.0f - wx1;
        float wy1 = iy - y0f, wy0 = 1.0f - wy1;
        int x0 = (int)x0f, y0 = (int)y0f;
        int x1 = x0 + 1,   y1 = y0 + 1;
        float a = aw[pt];
        float vx0 = (x0 >= 0 && x0 <= 63) ? 1.f : 0.f;
        float vx1 = (x1 >= 0 && x1 <= 63) ? 1.f : 0.f;
        float vy0 = (y0 >= 0 && y0 <= 63) ? 1.f : 0.f;
        float vy1 = (y1 >= 0 && y1 <= 63) ? 1.f : 0.f;
        float w00 = a * wy0 * wx0 * vy0 * vx0;
        float w01 = a * wy0 * wx1 * vy0 * vx1;
        float w10 = a * wy1 * wx0 * vy1 * vx0;
        float w11 = a * wy1 * wx1 * vy1 * vx1;
        int cx0 = min(max(x0, 0), 63), cx1 = min(max(x1, 0), 63);
        int cy0 = min(max(y0, 0), 63), cy1 = min(max(y1, 0), 63);
        ushort4 u00 = *(const ushort4*)&vb[(size_t)(cy0 * 64 + cx0) * 32];
        ushort4 u01 = *(const ushort4*)&vb[(size_t)(cy0 * 64 + cx1) * 32];
        ushort4 u10 = *(const ushort4*)&vb[(size_t)(cy1 * 64 + cx0) * 32];
        ushort4 u11 = *(const ushort4*)&vb[(size_t)(cy1 * 64 + cx1) * 32];
        acc.x += w00 * bf2f(u00.x) + w01 * bf2f(u01.x) + w10 * bf2f(u10.x) + w11 * bf2f(u11.x);
        acc.y += w00 * bf2f(u00.y) + w01 * bf2f(u01.y) + w10 * bf2f(u10.y) + w11 * bf2f(u11.y);
        acc.z += w00 * bf2f(u00.z) + w01 * bf2f(u01.z) + w10 * bf2f(u10.z) + w11 * bf2f(u11.z);
        acc.w += w00 * bf2f(u00.w) + w01 * bf2f(u01.w) + w10 * bf2f(u10.w) + w11 * bf2f(u11.w);
    }

    ushort4 st = make_ushort4(f2bf(acc.x), f2bf(acc.y), f2bf(acc.z), f2bf(acc.w));
    *(ushort4*)&wgt_t[((size_t)b * HW + p) * 256 + head * 32 + c4 * 4] = st;
}

// ---------------------------------------------------------------------------
// GEMM2: output projection + bias + residual. grid = 8(b)*2(mt)*32(pt) = 512
// ---------------------------------------------------------------------------
__global__ __launch_bounds__(256)
void outproj_gemm(const unsigned short* __restrict__ wout_bf, const unsigned short* __restrict__ wgt_t,
                  const float* __restrict__ b_out, const float* __restrict__ x,
                  float* __restrict__ out)
{
    __shared__ unsigned short Al[128 * 64];
    __shared__ unsigned short Bl[128 * 64];
    const int bid = blockIdx.x;
    const int pt = bid & 31, mt = (bid >> 5) & 1, b = bid >> 6;
    const int tid = threadIdx.x, wid = tid >> 6, lane = tid & 63;
    const int wm = wid >> 1, wn = wid & 1;
    const int mloc = lane & 15, ksel = lane >> 4;

    const unsigned short* Ag = wout_bf + mt * 128 * 256;
    const unsigned short* Bg = wgt_t + ((size_t)b * HW + pt * 128) * 256;

    f32x4 acc[4][4];
#pragma unroll
    for (int fm = 0; fm < 4; ++fm)
#pragma unroll
        for (int fn = 0; fn < 4; ++fn) acc[fm][fn] = (f32x4){0.f, 0.f, 0.f, 0.f};

    mfma_loop2(Ag, Bg, Al, Bl, wid, lane, wm, wn, acc);

#pragma unroll
    for (int fm = 0; fm < 4; ++fm) {
        const int o = mt * 128 + wm * 64 + fm * 16 + ksel * 4;
        float4 bo = *(const float4*)&b_out[o];
#pragma unroll
        for (int fn = 0; fn < 4; ++fn) {
            const int p = pt * 128 + wn * 64 + fn * 16 + mloc;
            const size_t idx = ((size_t)(b * 256 + o)) * HW + p;
            f32x4 v = acc[fm][fn];
            out[idx + 0 * HW] = v[0] + bo.x + x[idx + 0 * HW];
            out[idx + 1 * HW] = v[1] + bo.y + x[idx + 1 * HW];
            out[idx + 2 * HW] = v[2] + bo.z + x[idx + 2 * HW];
            out[idx + 3 * HW] = v[3] + bo.w + x[idx + 3 * HW];
        }
    }
}

// ---------------------------------------------------------------------------
extern "C" void kernel_launch(void* const* d_in, const int* in_sizes, int n_in,
                              void* d_out, int out_size, void* d_ws, size_t ws_size,
                              hipStream_t stream)
{
    const float* x      = (const float*)d_in[0];
    const float* w_off  = (const float*)d_in[1];
    const float* b_off  = (const float*)d_in[2];
    const float* w_attn = (const float*)d_in[3];
    const float* b_attn = (const float*)d_in[4];
    const float* w_val  = (const float*)d_in[5];
    const float* b_val  = (const float*)d_in[6];
    const float* w_out  = (const float*)d_in[7];
    const float* b_out  = (const float*)d_in[8];
    float* out = (float*)d_out;

    char* ws = (char*)d_ws;
    unsigned short* wcat_bf = (unsigned short*)(ws + 0);          //  196608 B
    unsigned short* wauxlo  = (unsigned short*)(ws + 196608);     //   65536 B
    unsigned short* wout_bf = (unsigned short*)(ws + 262144);     //  131072 B
    float*          bcat    = (float*)(ws + 393216);              //    2048 B
    unsigned short* xhi     = (unsigned short*)(ws + 395264);     // 16777216 B
    unsigned short* xlo     = (unsigned short*)(ws + 17172480);   // 16777216 B
    unsigned short* val_bf  = (unsigned short*)(ws + 33949696);   // 16777216 B
    float*          off_ws  = (float*)(ws + 50726912);            //  8388608 B
    float*          attn_ws = (float*)(ws + 59115520);            //  4194304 B
    unsigned short* wgt_t   = (unsigned short*)(ws + 63309824);   // 16777216 B  (end ~80.1 MB)

    prep_kernel<<<384, 256, 0, stream>>>(w_off, b_off, w_attn, b_attn, w_val, b_val,
                                         w_out, wcat_bf, wauxlo, wout_bf, bcat);
    transpose_kernel<<<2048, 256, 0, stream>>>(x, xhi, xlo);
    value_gemm<<<512, 256, 0, stream>>>(wcat_bf, xhi, bcat, val_bf);
    offattn_gemm<<<256, 256, 0, stream>>>(wcat_bf, wauxlo, xhi, xlo, bcat, off_ws, attn_ws);
    sample_kernel<<<8192, 256, 0, stream>>>(val_bf, off_ws, attn_ws, wgt_t);
    outproj_gemm<<<512, 256, 0, stream>>>(wout_bf, wgt_t, b_out, x, out);
}